// Round 5
// baseline (211.286 us; speedup 1.0000x reference)
//
#include <hip/hip_runtime.h>
#include <hip/hip_bf16.h>
#include <cstdint>
#include <cstddef>

#define NB 2048
#define NT 200
#define ND 64
#define NH1 128
#define NH2 64
#define NTILES 7
#define NTP 224

typedef __bf16 bf16x8 __attribute__((ext_vector_type(8)));
typedef float f32x4 __attribute__((ext_vector_type(4)));

#define MFMA16(A, Bv, C) __builtin_amdgcn_mfma_f32_16x16x32_bf16((A), (Bv), (C), 0, 0, 0)

union BF8u { __bf16 b[8]; bf16x8 v; uint4 u4; };

// sum over the 16-lane DPP row (circulant rotate-add); result in every lane
template<int N>
__device__ __forceinline__ float row_ror_add(float v) {
    int r = __builtin_amdgcn_update_dpp(0, __builtin_bit_cast(int, v),
                                        0x120 | N, 0xF, 0xF, false);
    return v + __builtin_bit_cast(float, r);
}

// prep: Qp[c][j] = (W1q+W1d)[c][j]; AbT[j][c] = (W1k-W1d)[c][j];
//       PT[j][c] = W1prod[c][j];    W2t[h2][k] = bf16(W2[k][h2])
__global__ void prep_kernel(const float* __restrict__ W1, const float* __restrict__ W2,
                            float* __restrict__ Qp, float* __restrict__ AbT,
                            float* __restrict__ PT, __bf16* __restrict__ W2t) {
    int tid = blockIdx.x * blockDim.x + threadIdx.x;
    if (tid < 64 * NH1) {
        int c = tid >> 7, j = tid & 127;
        Qp[tid] = W1[c * NH1 + j] + W1[(128 + c) * NH1 + j];
        int jj = tid >> 6, cc = tid & 63;
        AbT[tid] = W1[(64 + cc) * NH1 + jj] - W1[(128 + cc) * NH1 + jj];
        PT[tid]  = W1[(192 + cc) * NH1 + jj];
        int j2 = tid >> 7, k = tid & 127;
        W2t[tid] = (__bf16)W2[k * NH2 + j2];
    }
}

// LDS pool (17664 B -> LDS no longer the occupancy cap; 8 blocks/CU possible):
//  [0,     4608)  KHI[32][72] bf16      (aliased by SCORES[224] f32 after main loop)
//  [4608, 13312)  H1 [32][136] bf16     (aliased by REDS[16][72] f32 in epilogue)
//  [13312,16896)  SP [4][224] f32
//  [16896,17152)  QS [64] f32
//  [17152,17664)  QHS[128] f32
__global__ __launch_bounds__(256, 8)
void attn_main(const float* __restrict__ query, const float* __restrict__ key,
               const float* __restrict__ value, const int* __restrict__ mask,
               const float* __restrict__ b1, const float* __restrict__ b2,
               const float* __restrict__ Wo,
               const float* __restrict__ Qp, const float* __restrict__ AbT,
               const float* __restrict__ PT, const __bf16* __restrict__ W2t,
               float* __restrict__ out)
{
    __shared__ __align__(16) char smem[17664];
    auto KHI = (__bf16(*)[72])(smem);
    auto H1  = (__bf16(*)[136])(smem + 4608);
    auto SP  = (float(*)[NTP])(smem + 13312);
    float* QS  = (float*)(smem + 16896);
    float* QHS = (float*)(smem + 17152);
    float* SCORES = (float*)(smem);           // alias KHI (dead after main loop)
    auto REDS = (float(*)[72])(smem + 4608);  // alias H1  (dead after main loop)

    const int b = blockIdx.x;
    const int tid = threadIdx.x;
    const int lane = tid & 63;
    const int wave = tid >> 6;
    const int jn = lane & 15;
    const int g4 = lane >> 4;
    const int g8 = g4 * 8;

    // ---- k-tile staging (coalesced, LDS), depth-1 prefetch in registers ----
    const int r_st = tid >> 3;            // row 0..31
    const int c0   = (tid & 7) * 8;       // col 0..56
    const float* kp_base = key + (size_t)b * NT * ND + c0;
    float4 pf0, pf1;

    auto load_tile = [&](int t0) {
        int t = t0 + r_st;
        t = t < NT ? t : NT - 1;          // clamp: rows >=NT give garbage, masked later
        const float* kp = kp_base + (size_t)t * ND;
        pf0 = *(const float4*)(kp);
        pf1 = *(const float4*)(kp + 4);
    };
    auto store_tile = [&]() {
        const float vals[8] = {pf0.x, pf0.y, pf0.z, pf0.w, pf1.x, pf1.y, pf1.z, pf1.w};
        BF8u ph;
        #pragma unroll
        for (int i = 0; i < 8; ++i) ph.b[i] = (__bf16)vals[i];
        *(uint4*)(&KHI[r_st][c0]) = ph.u4;
    };

    load_tile(0);                          // HBM in flight immediately

    if (tid < ND) QS[tid] = query[(size_t)b * ND + tid];
    int mk = 0;
    if (tid < NT) mk = mask[(size_t)b * NT + tid];
    __syncthreads();                       // QS visible

    // qh = b1 + q.(W1q+W1d)
    if (tid < NH1) {
        float a = b1[tid];
        #pragma unroll 8
        for (int c = 0; c < ND; ++c) a = fmaf(QS[c], Qp[c * NH1 + tid], a);
        QHS[tid] = a;
    }

    // GEMM1 B-frags: B_b[c][j] = AbT[j][c] + q[c]*PT[j][c], bf16 hi+lo, registers.
    // wave owns h1 columns [32*wave, 32*wave+32)
    bf16x8 g1_bhi[2][2], g1_blo[2][2];
    const int jown = wave * 32;
    #pragma unroll
    for (int n = 0; n < 2; ++n) {
        const int j = jown + n * 16 + jn;
        #pragma unroll
        for (int kk = 0; kk < 2; ++kk) {
            const float* ab = AbT + j * ND + kk * 32 + g8;
            const float* pt = PT  + j * ND + kk * 32 + g8;
            float4 a0 = *(const float4*)ab, a1 = *(const float4*)(ab + 4);
            float4 p0 = *(const float4*)pt, p1 = *(const float4*)(pt + 4);
            const float va[8] = {a0.x,a0.y,a0.z,a0.w,a1.x,a1.y,a1.z,a1.w};
            const float vp[8] = {p0.x,p0.y,p0.z,p0.w,p1.x,p1.y,p1.z,p1.w};
            BF8u vh, vl;
            #pragma unroll
            for (int e = 0; e < 8; ++e) {
                const int c = kk * 32 + g8 + e;
                float v = fmaf(QS[c], vp[e], va[e]);
                __bf16 hi = (__bf16)v;
                vh.b[e] = hi;
                vl.b[e] = (__bf16)(v - (float)hi);
            }
            g1_bhi[n][kk] = vh.v;
            g1_blo[n][kk] = vl.v;
        }
    }
    // GEMM2 B-frags (plain bf16 W2t); wave owns h2 cols [16w,16w+16)
    bf16x8 g2_w[4];
    {
        const int j2 = wave * 16 + jn;
        #pragma unroll
        for (int kk = 0; kk < 4; ++kk)
            g2_w[kk] = *(const bf16x8*)(W2t + j2 * NH1 + kk * 32 + g8);
    }
    __syncthreads();                       // QHS visible (and QS reads done)
    const float qh0 = QHS[jown + jn];
    const float qh1 = QHS[jown + 16 + jn];
    const float b2j = b2[wave * 16 + jn];
    const float woj = Wo[wave * 16 + jn];

    for (int ti = 0; ti < NTILES; ++ti) {
        store_tile();                                  // publish k(ti)
        if (ti + 1 < NTILES) load_tile((ti + 1) * 32); // k(ti+1) in flight over G1+G2
        __syncthreads();                               // KHI ready; prev H1 reads done

        // ---- GEMM1: h1 = relu(qh + k @ B_b); 2 chains x 2 MFMA ----
        #pragma unroll
        for (int mt = 0; mt < 2; ++mt) {
            const int arow = mt * 16 + jn;
            const bf16x8 a0 = *(const bf16x8*)(&KHI[arow][g8]);
            const bf16x8 a1 = *(const bf16x8*)(&KHI[arow][32 + g8]);
            #pragma unroll
            for (int n = 0; n < 2; ++n) {
                f32x4 acA = {0.f,0.f,0.f,0.f}, acB = {0.f,0.f,0.f,0.f};
                acA = MFMA16(a0, g1_bhi[n][0], acA);
                acB = MFMA16(a1, g1_bhi[n][1], acB);
                acA = MFMA16(a0, g1_blo[n][0], acA);
                acB = MFMA16(a1, g1_blo[n][1], acB);
                const float qhj = n ? qh1 : qh0;
                const int j = jown + n * 16 + jn;
                #pragma unroll
                for (int r = 0; r < 4; ++r)
                    H1[mt * 16 + g4 * 4 + r][j] = (__bf16)fmaxf(acA[r] + acB[r] + qhj, 0.f);
            }
        }
        __syncthreads();                               // H1 ready

        // ---- GEMM2 + score: s = relu(h1@W2 + b2) . Wo ; DPP 16-lane reduce ----
        const int t0 = ti * 32;
        #pragma unroll
        for (int mt = 0; mt < 2; ++mt) {
            const int arow = mt * 16 + jn;
            bf16x8 h[4];
            #pragma unroll
            for (int kk = 0; kk < 4; ++kk)
                h[kk] = *(const bf16x8*)(&H1[arow][kk * 32 + g8]);
            f32x4 cA = {0.f,0.f,0.f,0.f}, cB = {0.f,0.f,0.f,0.f};
            cA = MFMA16(h[0], g2_w[0], cA);
            cB = MFMA16(h[1], g2_w[1], cB);
            cA = MFMA16(h[2], g2_w[2], cA);
            cB = MFMA16(h[3], g2_w[3], cB);
            #pragma unroll
            for (int r = 0; r < 4; ++r) {
                float v = fmaxf(cA[r] + cB[r] + b2j, 0.f) * woj;
                v = row_ror_add<8>(v);
                v = row_ror_add<4>(v);
                v = row_ror_add<2>(v);
                v = row_ror_add<1>(v);
                if (jn == 0) SP[wave][t0 + mt * 16 + g4 * 4 + r] = v;
            }
        }
    }
    __syncthreads();                       // all SP visible; KHI/H1 dead

    // ---- softmax numerator (no max-sub: |s| small, fp32 exp safe) ----
    if (tid < NTP) {
        const float sc = SP[0][tid] + SP[1][tid] + SP[2][tid] + SP[3][tid];
        SCORES[tid] = (tid < NT && mk != 0) ? __expf(sc) : 0.f;
    }
    __syncthreads();                       // SCORES ready

    // ---- out = (e @ V) / sum(e), denominator fused ----
    {
        const int tg = tid >> 4;
        const int dq = tid & 15;
        const float* vbase = value + (size_t)b * NT * ND + dq * 4;
        float oa0 = 0.f, oa1 = 0.f, oa2 = 0.f, oa3 = 0.f, den = 0.f;
        for (int t = tg; t < NT; t += 16) {
            const float e = SCORES[t];
            const float4 v4 = *(const float4*)(vbase + (size_t)t * ND);
            oa0 = fmaf(e, v4.x, oa0); oa1 = fmaf(e, v4.y, oa1);
            oa2 = fmaf(e, v4.z, oa2); oa3 = fmaf(e, v4.w, oa3);
            den += e;
        }
        REDS[tg][dq*4+0] = oa0; REDS[tg][dq*4+1] = oa1;
        REDS[tg][dq*4+2] = oa2; REDS[tg][dq*4+3] = oa3;
        if (dq == 0) REDS[tg][64] = den;
    }
    __syncthreads();

    if (tid < ND) {
        float s = 0.f, den = 0.f;
        #pragma unroll
        for (int g = 0; g < 16; ++g) { s += REDS[g][tid]; den += REDS[g][64]; }
        out[(size_t)b * ND + tid] = s / den;
    }
}

extern "C" void kernel_launch(void* const* d_in, const int* in_sizes, int n_in,
                              void* d_out, int out_size, void* d_ws, size_t ws_size,
                              hipStream_t stream) {
    const float* query = (const float*)d_in[0];
    const float* key   = (const float*)d_in[1];
    const float* value = (const float*)d_in[2];
    const int*   maskp = (const int*)d_in[3];
    const float* W1    = (const float*)d_in[4];
    const float* b1    = (const float*)d_in[5];
    const float* W2    = (const float*)d_in[6];
    const float* b2    = (const float*)d_in[7];
    const float* Wo    = (const float*)d_in[8];
    float* out = (float*)d_out;

    float* Qp  = (float*)d_ws;                 // 64*128 f32
    float* AbT = Qp + 64 * NH1;                // 128*64 f32
    float* PT  = AbT + NH1 * ND;               // 128*64 f32
    __bf16* W2t = (__bf16*)(PT + NH1 * ND);    // 64*128 bf16

    prep_kernel<<<32, 256, 0, stream>>>(W1, W2, Qp, AbT, PT, W2t);
    attn_main<<<NB, 256, 0, stream>>>(query, key, value, maskp, b1, b2, Wo,
                                      Qp, AbT, PT, W2t, out);
}

// Round 6
// 61.740 us; speedup vs baseline: 3.4222x; 3.4222x over previous
//
#include <hip/hip_runtime.h>
#include <hip/hip_bf16.h>
#include <cstdint>
#include <cstddef>

#define NB 2048
#define NT 200
#define ND 64
#define NH1 128
#define NH2 64
#define NTILES 7
#define NTP 224

typedef __bf16 bf16x8 __attribute__((ext_vector_type(8)));
typedef float f32x4 __attribute__((ext_vector_type(4)));

#define MFMA16(A, Bv, C) __builtin_amdgcn_mfma_f32_16x16x32_bf16((A), (Bv), (C), 0, 0, 0)

union BF8u { __bf16 b[8]; bf16x8 v; uint4 u4; };

// sum over the 16-lane DPP row (circulant rotate-add); result in every lane
template<int N>
__device__ __forceinline__ float row_ror_add(float v) {
    int r = __builtin_amdgcn_update_dpp(0, __builtin_bit_cast(int, v),
                                        0x120 | N, 0xF, 0xF, false);
    return v + __builtin_bit_cast(float, r);
}

// prep: Qp[c][j] = (W1q+W1d)[c][j]; AbT[j][c] = (W1k-W1d)[c][j];
//       PT[j][c] = W1prod[c][j];    W2t[h2][k] = bf16(W2[k][h2])
__global__ void prep_kernel(const float* __restrict__ W1, const float* __restrict__ W2,
                            float* __restrict__ Qp, float* __restrict__ AbT,
                            float* __restrict__ PT, __bf16* __restrict__ W2t) {
    int tid = blockIdx.x * blockDim.x + threadIdx.x;
    if (tid < 64 * NH1) {
        int c = tid >> 7, j = tid & 127;
        Qp[tid] = W1[c * NH1 + j] + W1[(128 + c) * NH1 + j];
        int jj = tid >> 6, cc = tid & 63;
        AbT[tid] = W1[(64 + cc) * NH1 + jj] - W1[(128 + cc) * NH1 + jj];
        PT[tid]  = W1[(192 + cc) * NH1 + jj];
        int j2 = tid >> 7, k = tid & 127;
        W2t[tid] = (__bf16)W2[k * NH2 + j2];
    }
}

// LDS pool (30976 B; 4 blocks/CU -> 124 KB/CU):
//  [0,     4608)  KHI0[32][72] bf16   (aliased by SCORES[224] f32 after main loop)
//  [4608,  9216)  KHI1[32][72] bf16
//  [9216, 17920)  H10 [32][136] bf16  (aliased by REDS[16][72] f32 in epilogue)
//  [17920,26624)  H11 [32][136] bf16
//  [26624,30208)  SP  [4][224] f32
//  [30208,30464)  QS  [64] f32
//  [30464,30976)  QHS [128] f32
__global__ __launch_bounds__(256, 4)
void attn_main(const float* __restrict__ query, const float* __restrict__ key,
               const float* __restrict__ value, const int* __restrict__ mask,
               const float* __restrict__ b1, const float* __restrict__ b2,
               const float* __restrict__ Wo,
               const float* __restrict__ Qp, const float* __restrict__ AbT,
               const float* __restrict__ PT, const __bf16* __restrict__ W2t,
               float* __restrict__ out)
{
    __shared__ __align__(16) char smem[30976];
    auto KHI0 = (__bf16(*)[72])(smem);
    auto KHI1 = (__bf16(*)[72])(smem + 4608);
    auto H10  = (__bf16(*)[136])(smem + 9216);
    auto H11  = (__bf16(*)[136])(smem + 17920);
    auto SP   = (float(*)[NTP])(smem + 26624);
    float* QS  = (float*)(smem + 30208);
    float* QHS = (float*)(smem + 30464);
    float* SCORES = (float*)(smem);            // alias KHI0 (dead after main loop)
    auto REDS = (float(*)[72])(smem + 9216);   // alias H10  (dead after main loop)

    const int b = blockIdx.x;
    const int tid = threadIdx.x;
    const int lane = tid & 63;
    const int wave = tid >> 6;
    const int jn = lane & 15;
    const int g4 = lane >> 4;
    const int g8 = g4 * 8;

    // ---- k-tile staging (coalesced, LDS double-buffer), depth-1 reg prefetch ----
    const int r_st = tid >> 3;            // row 0..31
    const int c0   = (tid & 7) * 8;       // col 0..56
    const float* kp_base = key + (size_t)b * NT * ND + c0;
    float4 pf0, pf1;

    auto load_tile = [&](int t0) {
        int t = t0 + r_st;
        t = t < NT ? t : NT - 1;          // clamp; garbage rows masked later
        const float* kp = kp_base + (size_t)t * ND;
        pf0 = *(const float4*)(kp);
        pf1 = *(const float4*)(kp + 4);
    };

    load_tile(0);                          // HBM in flight immediately

    if (tid < ND) QS[tid] = query[(size_t)b * ND + tid];
    int mk = 0;
    if (tid < NT) mk = mask[(size_t)b * NT + tid];
    __syncthreads();                       // QS visible

    // qh = b1 + q.(W1q+W1d)
    if (tid < NH1) {
        float a = b1[tid];
        #pragma unroll 8
        for (int c = 0; c < ND; ++c) a = fmaf(QS[c], Qp[c * NH1 + tid], a);
        QHS[tid] = a;
    }

    // GEMM1 B-frags: B_b[c][j] = AbT[j][c] + q[c]*PT[j][c], bf16 hi+lo, registers.
    // wave owns h1 columns [32*wave, 32*wave+32)
    bf16x8 g1_bhi[2][2], g1_blo[2][2];
    const int jown = wave * 32;
    #pragma unroll
    for (int n = 0; n < 2; ++n) {
        const int j = jown + n * 16 + jn;
        #pragma unroll
        for (int kk = 0; kk < 2; ++kk) {
            const float* ab = AbT + j * ND + kk * 32 + g8;
            const float* pt = PT  + j * ND + kk * 32 + g8;
            float4 a0 = *(const float4*)ab, a1 = *(const float4*)(ab + 4);
            float4 p0 = *(const float4*)pt, p1 = *(const float4*)(pt + 4);
            const float va[8] = {a0.x,a0.y,a0.z,a0.w,a1.x,a1.y,a1.z,a1.w};
            const float vp[8] = {p0.x,p0.y,p0.z,p0.w,p1.x,p1.y,p1.z,p1.w};
            BF8u vh, vl;
            #pragma unroll
            for (int e = 0; e < 8; ++e) {
                const int c = kk * 32 + g8 + e;
                float v = fmaf(QS[c], vp[e], va[e]);
                __bf16 hi = (__bf16)v;
                vh.b[e] = hi;
                vl.b[e] = (__bf16)(v - (float)hi);
            }
            g1_bhi[n][kk] = vh.v;
            g1_blo[n][kk] = vl.v;
        }
    }
    // GEMM2 B-frags (plain bf16 W2t); wave owns h2 cols [16w,16w+16)
    bf16x8 g2_w[4];
    {
        const int j2 = wave * 16 + jn;
        #pragma unroll
        for (int kk = 0; kk < 4; ++kk)
            g2_w[kk] = *(const bf16x8*)(W2t + j2 * NH1 + kk * 32 + g8);
    }
    __syncthreads();                       // QHS visible (and QS reads done)
    const float qh0 = QHS[jown + jn];
    const float qh1 = QHS[jown + 16 + jn];
    const float b2j = b2[wave * 16 + jn];
    const float woj = Wo[wave * 16 + jn];

    // ---- software-pipelined main loop: ONE barrier per iteration ----
    // iter ti: pre-barrier : publish k(ti) -> KLDS[ti&1], publish h1(ti-1) from accc
    //          post-barrier: issue k(ti+1) load; GEMM1(ti) -> accc; GEMM2(ti-1) -> SP
    f32x4 accc[2][2];
    for (int ti = 0; ti <= NTILES; ++ti) {
        __bf16 (*KCUR)[72]   = (ti & 1) ? KHI1 : KHI0;
        __bf16 (*H1CUR)[136] = ((ti - 1) & 1) ? H11 : H10;

        if (ti < NTILES) {                 // publish k(ti)
            const float vals[8] = {pf0.x, pf0.y, pf0.z, pf0.w, pf1.x, pf1.y, pf1.z, pf1.w};
            BF8u ph;
            #pragma unroll
            for (int i = 0; i < 8; ++i) ph.b[i] = (__bf16)vals[i];
            *(uint4*)(&KCUR[r_st][c0]) = ph.u4;
        }
        if (ti > 0) {                      // publish h1(ti-1) from carried accs
            #pragma unroll
            for (int mt = 0; mt < 2; ++mt)
            #pragma unroll
            for (int n = 0; n < 2; ++n) {
                const float qhj = n ? qh1 : qh0;
                const int j = jown + n * 16 + jn;
                #pragma unroll
                for (int r = 0; r < 4; ++r)
                    H1CUR[mt * 16 + g4 * 4 + r][j] =
                        (__bf16)fmaxf(accc[mt][n][r] + qhj, 0.f);
            }
        }
        __syncthreads();                   // the ONE barrier

        if (ti + 1 < NTILES) load_tile((ti + 1) * 32);  // in flight over G1+G2

        if (ti < NTILES) {                 // GEMM1(ti): k @ B_b -> accc
            #pragma unroll
            for (int mt = 0; mt < 2; ++mt) {
                const int arow = mt * 16 + jn;
                const bf16x8 a0 = *(const bf16x8*)(&KCUR[arow][g8]);
                const bf16x8 a1 = *(const bf16x8*)(&KCUR[arow][32 + g8]);
                #pragma unroll
                for (int n = 0; n < 2; ++n) {
                    f32x4 ac = {0.f, 0.f, 0.f, 0.f};
                    ac = MFMA16(a0, g1_bhi[n][0], ac);
                    ac = MFMA16(a1, g1_bhi[n][1], ac);
                    ac = MFMA16(a0, g1_blo[n][0], ac);
                    ac = MFMA16(a1, g1_blo[n][1], ac);
                    accc[mt][n] = ac;
                }
            }
        }
        if (ti > 0) {                      // GEMM2(ti-1) + score
            const int t0 = (ti - 1) * 32;
            #pragma unroll
            for (int mt = 0; mt < 2; ++mt) {
                const int arow = mt * 16 + jn;
                const bf16x8 h0v = *(const bf16x8*)(&H1CUR[arow][g8]);
                const bf16x8 h1v = *(const bf16x8*)(&H1CUR[arow][32 + g8]);
                const bf16x8 h2v = *(const bf16x8*)(&H1CUR[arow][64 + g8]);
                const bf16x8 h3v = *(const bf16x8*)(&H1CUR[arow][96 + g8]);
                f32x4 cA = {0.f,0.f,0.f,0.f}, cB = {0.f,0.f,0.f,0.f};
                cA = MFMA16(h0v, g2_w[0], cA);
                cB = MFMA16(h1v, g2_w[1], cB);
                cA = MFMA16(h2v, g2_w[2], cA);
                cB = MFMA16(h3v, g2_w[3], cB);
                #pragma unroll
                for (int r = 0; r < 4; ++r) {
                    float v = fmaxf(cA[r] + cB[r] + b2j, 0.f) * woj;
                    v = row_ror_add<8>(v);
                    v = row_ror_add<4>(v);
                    v = row_ror_add<2>(v);
                    v = row_ror_add<1>(v);
                    if (jn == 0) SP[wave][t0 + mt * 16 + g4 * 4 + r] = v;
                }
            }
        }
    }
    __syncthreads();                       // all SP visible; K/H1 buffers dead

    // ---- softmax numerator (no max-sub: |s| small, fp32 exp safe) ----
    if (tid < NTP) {
        const float sc = SP[0][tid] + SP[1][tid] + SP[2][tid] + SP[3][tid];
        SCORES[tid] = (tid < NT && mk != 0) ? __expf(sc) : 0.f;
    }
    __syncthreads();                       // SCORES ready

    // ---- out = (e @ V) / sum(e), denominator fused ----
    {
        const int tg = tid >> 4;
        const int dq = tid & 15;
        const float* vbase = value + (size_t)b * NT * ND + dq * 4;
        float oa0 = 0.f, oa1 = 0.f, oa2 = 0.f, oa3 = 0.f, den = 0.f;
        for (int t = tg; t < NT; t += 16) {
            const float e = SCORES[t];
            const float4 v4 = *(const float4*)(vbase + (size_t)t * ND);
            oa0 = fmaf(e, v4.x, oa0); oa1 = fmaf(e, v4.y, oa1);
            oa2 = fmaf(e, v4.z, oa2); oa3 = fmaf(e, v4.w, oa3);
            den += e;
        }
        REDS[tg][dq*4+0] = oa0; REDS[tg][dq*4+1] = oa1;
        REDS[tg][dq*4+2] = oa2; REDS[tg][dq*4+3] = oa3;
        if (dq == 0) REDS[tg][64] = den;
    }
    __syncthreads();

    if (tid < ND) {
        float s = 0.f, den = 0.f;
        #pragma unroll
        for (int g = 0; g < 16; ++g) { s += REDS[g][tid]; den += REDS[g][64]; }
        out[(size_t)b * ND + tid] = s / den;
    }
}

extern "C" void kernel_launch(void* const* d_in, const int* in_sizes, int n_in,
                              void* d_out, int out_size, void* d_ws, size_t ws_size,
                              hipStream_t stream) {
    const float* query = (const float*)d_in[0];
    const float* key   = (const float*)d_in[1];
    const float* value = (const float*)d_in[2];
    const int*   maskp = (const int*)d_in[3];
    const float* W1    = (const float*)d_in[4];
    const float* b1    = (const float*)d_in[5];
    const float* W2    = (const float*)d_in[6];
    const float* b2    = (const float*)d_in[7];
    const float* Wo    = (const float*)d_in[8];
    float* out = (float*)d_out;

    float* Qp  = (float*)d_ws;                 // 64*128 f32
    float* AbT = Qp + 64 * NH1;                // 128*64 f32
    float* PT  = AbT + NH1 * ND;               // 128*64 f32
    __bf16* W2t = (__bf16*)(PT + NH1 * ND);    // 64*128 bf16

    prep_kernel<<<32, 256, 0, stream>>>(W1, W2, Qp, AbT, PT, W2t);
    attn_main<<<NB, 256, 0, stream>>>(query, key, value, maskp, b1, b2, Wo,
                                      Qp, AbT, PT, W2t, out);
}